// Round 14
// baseline (236.881 us; speedup 1.0000x reference)
//
#include <hip/hip_runtime.h>

#define BB 4
#define HH 8
#define LL 8192
#define NN (BB*LL)
#define DDIM 32
#define MM 128

// ws layout (float offsets)
#define CTXR_OFF 0                          // 32*8*128*4 = 131072
#define KSUMR_OFF (CTXR_OFF + 32*8*MM*4)    // 4096
#define VSUM_OFF  (KSUMR_OFF + 32*MM)       // 1024
#define GMAX_OFF  (VSUM_OFF + 32*32)        // 1
#define ZERO_FLOATS (GMAX_OFF + 1)

#define DN 0.42044820762685725f             // 32^-0.25
#define RATIO 0.08838834764831845f          // 128^-0.5
#define EPSF 1e-4f

__device__ __forceinline__ float rl(float x, int l) {
    return __uint_as_float(__builtin_amdgcn_readlane(__float_as_uint(x), l));
}
__device__ __forceinline__ float rl4(float4 v, int c, int l) {
    const float x = (c==0) ? v.x : (c==1) ? v.y : (c==2) ? v.z : v.w;
    return rl(x, l);
}

// ------- k1: raw ctx/ksum/vsum/gmax.
// R14: NO scalar-mem row loads (R11-R13 stalled ~70% on lgkmcnt: SMEM can't
// pipeline). Per 32-row batch: 10 coalesced global_load_dwordx4 put k/v in
// VGPRs (vmcnt-pipelined, latency exposed once/batch), rows consumed via
// v_readlane broadcasts (pure VALU). No LDS/barriers in main loop.
__global__ __launch_bounds__(256, 2) void k_ctx1(const float* __restrict__ kk0,
                                                 const float* __restrict__ kk1,
                                                 const float* __restrict__ v0,
                                                 const float* __restrict__ v1,
                                                 const float* __restrict__ w,
                                                 float* __restrict__ ws) {
    __shared__ float red[2][64][34];
    const int tid = threadIdx.x;
    const int lane = tid & 63;
    const int wid  = __builtin_amdgcn_readfirstlane(tid >> 6);
    const int half = wid & 1, rgrp = wid >> 1;
    const int m = half*64 + lane;
    const int bh = blockIdx.x >> 5, chunk = blockIdx.x & 31;
    const int b = bh >> 3, h = bh & 7;
    const int n0 = b*LL + chunk*256 + rgrp*128;
    float wreg[32];                           // w * DN
    {
        const float4* w4 = (const float4*)(w + m*DDIM);
#pragma unroll
        for (int q = 0; q < 8; ++q) {
            const float4 t = w4[q];
            wreg[q*4+0]=t.x*DN; wreg[q*4+1]=t.y*DN;
            wreg[q*4+2]=t.z*DN; wreg[q*4+3]=t.w*DN;
        }
    }
    // static per-lane load offsets (in floats)
    const int rowA = lane >> 1, qA = lane & 1;            // k0/v0: 32 rows x 2 lanes
    const int offA = rowA*64 + h*8 + qA*4;
    const int rowB = lane >> 3, qB = lane & 7;            // k1/v1: 8 rows x 8 lanes
    const int offB = rowB*192 + h*24 + ((qB < 6) ? qB*4 : 20);
    float acc[32];
#pragma unroll
    for (int i = 0; i < 32; ++i) acc[i] = 0.f;
    float ksum_acc = 0.f, vsum_acc = 0.f, wmax = -3.4e38f;
#pragma unroll 1
    for (int bi = 0; bi < 4; ++bi) {
        const int nb = n0 + bi*32;
        // ---- batch loads: 10 coalesced dwordx4, all in flight together ----
        const float4 k0b = *(const float4*)(kk0 + (size_t)nb*64 + offA);
        const float4 v0b = *(const float4*)(v0  + (size_t)nb*64 + offA);
        float4 k1b[4], v1b[4];
#pragma unroll
        for (int j = 0; j < 4; ++j) {
            k1b[j] = *(const float4*)(kk1 + (size_t)nb*192 + j*1536 + offB);
            v1b[j] = *(const float4*)(v1  + (size_t)nb*192 + j*1536 + offB);
        }
        // ---- diag for 32 rows (two 16-row passes, R11 pattern) ----
        float diagv0, diagv1;
#pragma unroll
        for (int dp = 0; dp < 2; ++dp) {
            const int dr_ = lane >> 2, dq = lane & 3;
            const int n = nb + dp*16 + dr_;
            float4 da, db;
            if (dq == 0) {
                da = *(const float4*)(kk0 + (size_t)n*64 + h*8);
                db = *(const float4*)(kk0 + (size_t)n*64 + h*8 + 4);
            } else {
                const float* bp = kk1 + (size_t)n*192 + h*24 + (dq-1)*8;
                da = *(const float4*)bp; db = *(const float4*)(bp + 4);
            }
            float ss = da.x*da.x+da.y*da.y+da.z*da.z+da.w*da.w
                     + db.x*db.x+db.y*db.y+db.z*db.z+db.w*db.w;
            ss += __shfl_xor(ss, 1); ss += __shfl_xor(ss, 2);
            const float dv_ = 0.5f*DN*DN*ss;
            if (dp == 0) diagv0 = dv_; else diagv1 = dv_;
        }
        // ---- vsum (half0 waves): two 16-row passes ----
        if (half == 0) {
            const int ve = lane & 31, vg = lane >> 5;
#pragma unroll
            for (int dp = 0; dp < 2; ++dp)
#pragma unroll
                for (int rr = 0; rr < 8; ++rr) {
                    const int n = nb + dp*16 + vg*8 + rr;
                    vsum_acc += (ve < 8) ? v0[(size_t)n*64 + h*8 + ve]
                                         : v1[(size_t)n*192 + h*24 + (ve-8)];
                }
        }
        // ---- consume 32 rows via readlane broadcasts ----
#pragma unroll
        for (int rq = 0; rq < 4; ++rq) {
#pragma unroll
            for (int rr = 0; rr < 8; ++rr) {
                const int r = rq*8 + rr;
                const float dg = rl((r < 16) ? diagv0 : diagv1, (r & 15)*4);
                float dd0 = 0.f, dd1 = 0.f;
#pragma unroll
                for (int d = 0; d < 8; ++d) {
                    const float s = rl4(k0b, d & 3, r*2 + (d >> 2));
                    if (d & 1) dd1 = fmaf(s, wreg[d], dd1);
                    else       dd0 = fmaf(s, wreg[d], dd0);
                }
#pragma unroll
                for (int e = 0; e < 24; ++e) {
                    const float s = rl4(k1b[rq], e & 3, rr*8 + (e >> 2));
                    if (e & 1) dd1 = fmaf(s, wreg[8+e], dd1);
                    else       dd0 = fmaf(s, wreg[8+e], dd0);
                }
                const float dd = dd0 + dd1;
                wmax = fmaxf(wmax, dd);
                const float kp = __expf(dd - dg);
                ksum_acc += kp;
#pragma unroll
                for (int c = 0; c < 8; ++c) {
                    const float av = rl4(v0b, c & 3, r*2 + (c >> 2));
                    acc[c*4] = fmaf(kp, av, acc[c*4]);
                }
#pragma unroll
                for (int e = 0; e < 24; ++e) {
                    const float av = rl4(v1b[rq], e & 3, rr*8 + (e >> 2));
                    const int ai = (e/3)*4 + 1 + e%3;
                    acc[ai] = fmaf(kp, av, acc[ai]);
                }
            }
        }
    }
    // ---- combine rgrp pairs in LDS, one atomic set per block ----
    if (rgrp == 1) {
#pragma unroll
        for (int i = 0; i < 32; ++i) red[half][lane][i] = acc[i];
        red[half][lane][32] = ksum_acc;
        red[half][lane][33] = vsum_acc;
    }
    __syncthreads();
    if (rgrp == 0) {
#pragma unroll
        for (int i = 0; i < 32; ++i) acc[i] += red[half][lane][i];
        ksum_acc += red[half][lane][32];
        vsum_acc += red[half][lane][33];
        float* ctxr = ws + CTXR_OFF;
#pragma unroll
        for (int c = 0; c < 8; ++c)
#pragma unroll
            for (int j = 0; j < 4; ++j)
                atomicAdd(&ctxr[((bh*8 + c)*MM + m)*4 + j], acc[c*4+j]);
        atomicAdd(ws + KSUMR_OFF + bh*MM + m, ksum_acc);
        if (half == 0) {
            const int ve = lane & 31;
            const int packed = (ve < 8) ? ve*4
                                        : ((ve-8)/3)*4 + 1 + (ve-8)%3;
            atomicAdd(ws + VSUM_OFF + bh*32 + packed, vsum_acc);
        }
    }
#pragma unroll
    for (int off = 32; off; off >>= 1) wmax = fmaxf(wmax, __shfl_xor(wmax, off, 64));
    if (lane == 0) {
        unsigned u = __float_as_uint(wmax);
        u = (u & 0x80000000u) ? ~u : (u | 0x80000000u);
        atomicMax((unsigned*)(ws + GMAX_OFF), u);
    }
}

// ------- k3: row-per-lane (unchanged from R11: ~75us)
__global__ __launch_bounds__(256, 2) void k_out(const float* __restrict__ kk0,
                                                const float* __restrict__ kk1,
                                                const float* __restrict__ w,
                                                const float* __restrict__ ws,
                                                float* __restrict__ out) {
    __shared__ float ctx_s[128*36];   // [m][p], pad 36 (b128-aligned rows)
    __shared__ float wlds[128*36];    // [m][d]*DN, pad 36
    __shared__ float ksl[128];
    __shared__ __align__(16) float sS0[32];
    __shared__ float sK0;
    const int tid = threadIdx.x;
    const int bh = blockIdx.x >> 5, chunk = blockIdx.x & 31;
    const int b = bh >> 3, h = bh & 7;
    const unsigned gu = *((const unsigned*)(ws + GMAX_OFF));
    const float gm = (gu & 0x80000000u) ? __uint_as_float(gu & 0x7fffffffu)
                                        : __uint_as_float(~gu);
    const float alpha = __expf(-gm);
    const float4* ctxr4 = (const float4*)(ws + CTXR_OFF) + (size_t)bh*1024;
    const float* vsg = ws + VSUM_OFF + bh*32;
#pragma unroll
    for (int it = 0; it < 4; ++it) {
        const int i = tid + it*256;          // 0..1023 float4s, [c][m]
        const int c = i >> 7, mm2 = i & 127;
        const float4 q = ctxr4[i];
        const int p0 = c*4;
        ctx_s[mm2*36+p0+0] = RATIO*(alpha*q.x + EPSF*vsg[p0+0]);
        ctx_s[mm2*36+p0+1] = RATIO*(alpha*q.y + EPSF*vsg[p0+1]);
        ctx_s[mm2*36+p0+2] = RATIO*(alpha*q.z + EPSF*vsg[p0+2]);
        ctx_s[mm2*36+p0+3] = RATIO*(alpha*q.w + EPSF*vsg[p0+3]);
    }
    {
        const float4* w4 = (const float4*)w;
#pragma unroll
        for (int it = 0; it < 4; ++it) {
            const int i = tid + it*256;      // [m][q]
            const int mm2 = i >> 3, q = i & 7;
            float4 t = w4[i];
            t.x*=DN; t.y*=DN; t.z*=DN; t.w*=DN;
            *(float4*)&wlds[mm2*36+q*4] = t;
        }
    }
    if (tid < 128) ksl[tid] = RATIO*(alpha*ws[KSUMR_OFF + bh*MM + tid] + EPSF*(float)LL);
    __syncthreads();
    if (tid < 32) {
        float s = 0.f;
#pragma unroll 8
        for (int mm2 = 0; mm2 < 128; ++mm2) s += ctx_s[mm2*36 + tid];
        sS0[tid] = s;
    } else if (tid < 64) {
        const int p2 = tid - 32;
        float s = ksl[p2] + ksl[32+p2] + ksl[64+p2] + ksl[96+p2];
        s += __shfl_xor(s, 1); s += __shfl_xor(s, 2); s += __shfl_xor(s, 4);
        s += __shfl_xor(s, 8); s += __shfl_xor(s, 16);
        if (p2 == 0) sK0 = s;
    }
    __syncthreads();
    const int n = b*LL + chunk*256 + tid;
    float K[32];
    {
        const float4 f0 = *(const float4*)(kk0 + (size_t)n*64 + h*8);
        const float4 f1 = *(const float4*)(kk0 + (size_t)n*64 + h*8 + 4);
        K[0]=f0.x; K[1]=f0.y; K[2]=f0.z; K[3]=f0.w;
        K[4]=f1.x; K[5]=f1.y; K[6]=f1.z; K[7]=f1.w;
        const float4* g4p = (const float4*)(kk1 + (size_t)n*192 + h*24);
#pragma unroll
        for (int gq = 0; gq < 6; ++gq) {
            const float4 g = g4p[gq];
            K[8+gq*4+0]=g.x; K[8+gq*4+1]=g.y; K[8+gq*4+2]=g.z; K[8+gq*4+3]=g.w;
        }
    }
    float dg = 0.f;
#pragma unroll
    for (int d = 0; d < 32; ++d) dg = fmaf(K[d], K[d], dg);
    dg *= 0.5f*DN*DN;
    float S1[32];
#pragma unroll
    for (int i = 0; i < 32; ++i) S1[i] = 0.f;
    float den1 = 0.f, mx = -3.4e38f;
#pragma unroll 2
    for (int m2 = 0; m2 < 128; ++m2) {
        const float* wrow = &wlds[m2*36];
        float dd0 = 0.f, dd1 = 0.f;
#pragma unroll
        for (int q = 0; q < 8; ++q) {
            const float4 wv = *(const float4*)&wrow[q*4];
            dd0 = fmaf(K[q*4+0], wv.x, dd0);
            dd1 = fmaf(K[q*4+1], wv.y, dd1);
            dd0 = fmaf(K[q*4+2], wv.z, dd0);
            dd1 = fmaf(K[q*4+3], wv.w, dd1);
        }
        const float dd = dd0 + dd1;
        mx = fmaxf(mx, dd);
        const float E = __expf(dd - dg);
        den1 = fmaf(E, ksl[m2], den1);
        const float* crow = &ctx_s[m2*36];
#pragma unroll
        for (int q = 0; q < 8; ++q) {
            const float4 cv = *(const float4*)&crow[q*4];
            S1[q*4+0] = fmaf(E, cv.x, S1[q*4+0]);
            S1[q*4+1] = fmaf(E, cv.y, S1[q*4+1]);
            S1[q*4+2] = fmaf(E, cv.z, S1[q*4+2]);
            S1[q*4+3] = fmaf(E, cv.w, S1[q*4+3]);
        }
    }
    const float es = __expf(-mx);
    const float dinv = 1.f / fmaf(es, den1, EPSF*sK0);
    float v[32];
#pragma unroll
    for (int q = 0; q < 8; ++q) {
        const float4 s0 = *(const float4*)&sS0[q*4];
        v[q*4+0] = fmaf(es, S1[q*4+0], EPSF*s0.x)*dinv;
        v[q*4+1] = fmaf(es, S1[q*4+1], EPSF*s0.y)*dinv;
        v[q*4+2] = fmaf(es, S1[q*4+2], EPSF*s0.z)*dinv;
        v[q*4+3] = fmaf(es, S1[q*4+3], EPSF*s0.w)*dinv;
    }
    float* o0 = out + (size_t)n*64 + h*8;
    *(float4*)(o0)     = make_float4(v[0],  v[4],  v[8],  v[12]);
    *(float4*)(o0 + 4) = make_float4(v[16], v[20], v[24], v[28]);
    float* o1 = out + (size_t)NN*64 + (size_t)n*192 + h*24;
    *(float4*)(o1 +  0) = make_float4(v[1],  v[2],  v[3],  v[5]);
    *(float4*)(o1 +  4) = make_float4(v[6],  v[7],  v[9],  v[10]);
    *(float4*)(o1 +  8) = make_float4(v[11], v[13], v[14], v[15]);
    *(float4*)(o1 + 12) = make_float4(v[17], v[18], v[19], v[21]);
    *(float4*)(o1 + 16) = make_float4(v[22], v[23], v[25], v[26]);
    *(float4*)(o1 + 20) = make_float4(v[27], v[29], v[30], v[31]);
}

extern "C" void kernel_launch(void* const* d_in, const int* in_sizes, int n_in,
                              void* d_out, int out_size, void* d_ws, size_t ws_size,
                              hipStream_t stream) {
    const float* v0 = (const float*)d_in[0];
    const float* v1 = (const float*)d_in[1];
    const float* k0 = (const float*)d_in[2];
    const float* k1 = (const float*)d_in[3];
    const float* w  = (const float*)d_in[6];
    float* out = (float*)d_out;
    float* ws  = (float*)d_ws;
    hipMemsetAsync(ws, 0, (size_t)ZERO_FLOATS*sizeof(float), stream);
    k_ctx1<<<1024, 256, 0, stream>>>(k0, k1, v0, v1, w, ws);
    k_out <<<1024, 256, 0, stream>>>(k0, k1, w, ws, out);
}